// Round 7
// baseline (407.455 us; speedup 1.0000x reference)
//
#include <hip/hip_runtime.h>
#include <hip/hip_fp16.h>
#include <math.h>

#define NN     40000
#define NT0    20000
#define NE     640000
#define NHOPS  8
#define RCAP   64                             // fixed CSR capacity per node (max in-deg ~45)
#define GSTRIDE ((size_t)(NN + 1) * 128)      // elems per g buffer (row NN = dummy zero)

// ---------------- fused degree count + bucket (fixed-capacity rows, u16 entries) ----
__global__ void degbucket_kernel(const int* __restrict__ src, const int* __restrict__ dst,
                                 unsigned* __restrict__ out_deg, unsigned* __restrict__ cnt,
                                 unsigned short* __restrict__ csr, int E)
{
    int e = blockIdx.x * blockDim.x + threadIdx.x;
    if (e >= E) return;
    int s = src[e], d = dst[e];
    atomicAdd(&out_deg[s], 1u);
    unsigned p = atomicAdd(&cnt[d], 1u);
    if (p < RCAP) csr[(d << 6) + (int)p] = (unsigned short)s;
}

// ---------------- norms: ns = out_deg^-1/2, nsd = ns*nd, rns = sqrt(out_deg) ------
__global__ void norm_kernel(const unsigned* __restrict__ out_deg, const unsigned* __restrict__ in_deg,
                            float* __restrict__ ns, float* __restrict__ nsd,
                            float* __restrict__ rns, int n)
{
    int i = blockIdx.x * blockDim.x + threadIdx.x;
    if (i >= n) return;
    float od = fmaxf((float)out_deg[i], 1.0f);
    float s = rsqrtf(od);
    float d = rsqrtf(fmaxf((float)in_deg[i], 1.0f));
    ns[i] = s; nsd[i] = s * d; rns[i] = sqrtf(od);
}

// ---------------- zero the dummy row (NN) of all 9 g buffers ----------------
__global__ void zero_pad_kernel(__half* __restrict__ g)
{
    int t = blockIdx.x * blockDim.x + threadIdx.x;
    int k = t >> 7, j = t & 127;
    if (k < 9) g[(size_t)k * GSTRIDE + ((size_t)NN << 7) + j] = __float2half(0.f);
}

// ---------------- input projection -> g0 = h*ns (fp16, full-row layout) ----------
__global__ void proj_kernel(const float* __restrict__ feat, const float* __restrict__ W,
                            const float* __restrict__ b, const float* __restrict__ ns,
                            __half* __restrict__ g0, int row0, int K)
{
    int j = threadIdx.x;                 // output column 0..127
    int rbase = blockIdx.x * 8;
    extern __shared__ float xsm[];       // [8][K]
    for (int r = 0; r < 8; ++r)
        for (int k = j; k < K; k += 128)
            xsm[r * K + k] = feat[(size_t)(rbase + r) * K + k];
    __syncthreads();
    float bj = b[j];
    float acc[8];
#pragma unroll
    for (int r = 0; r < 8; ++r) acc[r] = bj;
    for (int k = 0; k < K; ++k) {
        float w = W[k * 128 + j];
#pragma unroll
        for (int r = 0; r < 8; ++r) acc[r] += xsm[r * K + k] * w;
    }
    for (int r = 0; r < 8; ++r) {
        int row = row0 + rbase + r;
        g0[((size_t)row << 7) + j] = __float2half(acc[r] * ns[row]);
    }
}

// ---------------- one hop: wave per node; 4 subgroups x 16 lanes x 16B; 16 edges/iter
__global__ __launch_bounds__(256) void hop_kernel(
    const __half* __restrict__ gc, __half* __restrict__ gn,
    const unsigned* __restrict__ ideg, const unsigned short* __restrict__ csr,
    const float* __restrict__ nsd)
{
    int node = blockIdx.x * 4 + (threadIdx.x >> 6);
    int lane = threadIdx.x & 63;
    int sub = lane >> 4;                  // edge slot 0..3
    int ch8 = lane & 15;                  // 16B chunk (8 halves) within the 256B row
    int deg = (int)ideg[node];
    int beg = node << 6;
    int end = beg + ((deg + 15) & ~15);   // padded iteration count

    float a[8] = {0.f, 0.f, 0.f, 0.f, 0.f, 0.f, 0.f, 0.f};
    for (int base = beg; base < end; base += 16) {
        int i = base + sub;
        // load csr entries (allocated memory; garbage past deg), then mask to dummy NN
        int s0 = (i      - beg < deg) ? (int)csr[i]      : NN;
        int s1 = (i + 4  - beg < deg) ? (int)csr[i + 4]  : NN;
        int s2 = (i + 8  - beg < deg) ? (int)csr[i + 8]  : NN;
        int s3 = (i + 12 - beg < deg) ? (int)csr[i + 12] : NN;
        int4 v0 = *(const int4*)(gc + ((size_t)s0 << 7) + (ch8 << 3));
        int4 v1 = *(const int4*)(gc + ((size_t)s1 << 7) + (ch8 << 3));
        int4 v2 = *(const int4*)(gc + ((size_t)s2 << 7) + (ch8 << 3));
        int4 v3 = *(const int4*)(gc + ((size_t)s3 << 7) + (ch8 << 3));
        float2 f;
        f = __half22float2(*(__half2*)&v0.x); a[0] += f.x; a[1] += f.y;
        f = __half22float2(*(__half2*)&v0.y); a[2] += f.x; a[3] += f.y;
        f = __half22float2(*(__half2*)&v0.z); a[4] += f.x; a[5] += f.y;
        f = __half22float2(*(__half2*)&v0.w); a[6] += f.x; a[7] += f.y;
        f = __half22float2(*(__half2*)&v1.x); a[0] += f.x; a[1] += f.y;
        f = __half22float2(*(__half2*)&v1.y); a[2] += f.x; a[3] += f.y;
        f = __half22float2(*(__half2*)&v1.z); a[4] += f.x; a[5] += f.y;
        f = __half22float2(*(__half2*)&v1.w); a[6] += f.x; a[7] += f.y;
        f = __half22float2(*(__half2*)&v2.x); a[0] += f.x; a[1] += f.y;
        f = __half22float2(*(__half2*)&v2.y); a[2] += f.x; a[3] += f.y;
        f = __half22float2(*(__half2*)&v2.z); a[4] += f.x; a[5] += f.y;
        f = __half22float2(*(__half2*)&v2.w); a[6] += f.x; a[7] += f.y;
        f = __half22float2(*(__half2*)&v3.x); a[0] += f.x; a[1] += f.y;
        f = __half22float2(*(__half2*)&v3.y); a[2] += f.x; a[3] += f.y;
        f = __half22float2(*(__half2*)&v3.z); a[4] += f.x; a[5] += f.y;
        f = __half22float2(*(__half2*)&v3.w); a[6] += f.x; a[7] += f.y;
    }
    // reduce across the 4 edge-subgroups (lanes 16, 32 apart)
#pragma unroll
    for (int j = 0; j < 8; ++j) {
        a[j] += __shfl_xor(a[j], 16);
        a[j] += __shfl_xor(a[j], 32);
    }
    if (sub == 0) {
        float k = nsd[node];
        __half2 h0 = __float22half2_rn(make_float2(a[0] * k, a[1] * k));
        __half2 h1 = __float22half2_rn(make_float2(a[2] * k, a[3] * k));
        __half2 h2 = __float22half2_rn(make_float2(a[4] * k, a[5] * k));
        __half2 h3 = __float22half2_rn(make_float2(a[6] * k, a[7] * k));
        int4 w;
        w.x = *(int*)&h0; w.y = *(int*)&h1; w.z = *(int*)&h2; w.w = *(int*)&h3;
        *(int4*)(gn + ((size_t)node << 7) + (ch8 << 3)) = w;
    }
}

// ---------------- finalize: x = sum_k g_k * rns / 9, LN0, Wp+ELU, LN1, Wo, L2 ----
// wave = 4 nodes; lane = (sub=node 2b, ck=16B chunk 4b). Wide int4 g-loads.
__global__ __launch_bounds__(256) void fin_kernel(
    const __half* __restrict__ g,        // 9 buffers, stride GSTRIDE
    const float* __restrict__ rns,
    const float* __restrict__ ln0g, const float* __restrict__ ln0b,
    const float* __restrict__ ln1g, const float* __restrict__ ln1b,
    const float* __restrict__ Wp, const float* __restrict__ bp,
    const float* __restrict__ Wo, const float* __restrict__ bo,
    float* __restrict__ out)
{
    __shared__ float xs[4][4][132];
    int wave = threadIdx.x >> 6, lane = threadIdx.x & 63;
    int sub = lane >> 4, ck = lane & 15;
    int node0 = blockIdx.x * 16 + wave * 4;
    int node = node0 + sub;
    int ch0 = ck << 3;                     // first of this lane's 8 channels

    // sum the 9 hop buffers: 9 x int4 (8 halves) per lane
    float s8[8] = {0,0,0,0,0,0,0,0};
#pragma unroll
    for (int k = 0; k < 9; ++k) {
        int4 v = *(const int4*)(g + (size_t)k * GSTRIDE + ((size_t)node << 7) + ch0);
        float2 f;
        f = __half22float2(*(__half2*)&v.x); s8[0] += f.x; s8[1] += f.y;
        f = __half22float2(*(__half2*)&v.y); s8[2] += f.x; s8[3] += f.y;
        f = __half22float2(*(__half2*)&v.z); s8[4] += f.x; s8[5] += f.y;
        f = __half22float2(*(__half2*)&v.w); s8[6] += f.x; s8[7] += f.y;
    }
    float sc = rns[node] * (1.0f / 9.0f);
#pragma unroll
    for (int i = 0; i < 8; ++i) s8[i] *= sc;

    // LN0: reduce within the 16-lane node group
    float t = 0.f;
#pragma unroll
    for (int i = 0; i < 8; ++i) t += s8[i];
#pragma unroll
    for (int m = 1; m < 16; m <<= 1) t += __shfl_xor(t, m);
    float mean = t * (1.0f / 128.0f);
    float q = 0.f;
#pragma unroll
    for (int i = 0; i < 8; ++i) { s8[i] -= mean; q += s8[i] * s8[i]; }
#pragma unroll
    for (int m = 1; m < 16; m <<= 1) q += __shfl_xor(q, m);
    float rstd = rsqrtf(q * (1.0f / 128.0f) + 1e-5f);
    float4 ga = *(const float4*)(ln0g + ch0);
    float4 gA = *(const float4*)(ln0g + ch0 + 4);
    float4 ba = *(const float4*)(ln0b + ch0);
    float4 bA = *(const float4*)(ln0b + ch0 + 4);
    xs[wave][sub][ch0 + 0] = s8[0] * rstd * ga.x + ba.x;
    xs[wave][sub][ch0 + 1] = s8[1] * rstd * ga.y + ba.y;
    xs[wave][sub][ch0 + 2] = s8[2] * rstd * ga.z + ba.z;
    xs[wave][sub][ch0 + 3] = s8[3] * rstd * ga.w + ba.w;
    xs[wave][sub][ch0 + 4] = s8[4] * rstd * gA.x + bA.x;
    xs[wave][sub][ch0 + 5] = s8[5] * rstd * gA.y + bA.y;
    xs[wave][sub][ch0 + 6] = s8[6] * rstd * gA.z + bA.z;
    xs[wave][sub][ch0 + 7] = s8[7] * rstd * gA.w + bA.w;

    // GEMV Wp (lane owns output cols c0,c1 for all 4 nodes of its wave)
    int c0 = lane * 2, c1 = c0 + 1;
    float a0[4], a1[4];
    float bp0 = bp[c0], bp1 = bp[c1];
#pragma unroll
    for (int n = 0; n < 4; ++n) { a0[n] = bp0; a1[n] = bp1; }
#pragma unroll 16
    for (int k = 0; k < 128; ++k) {
        float2 w = *(const float2*)(Wp + k * 128 + c0);
#pragma unroll
        for (int n = 0; n < 4; ++n) {
            float xk = xs[wave][n][k];
            a0[n] += xk * w.x; a1[n] += xk * w.y;
        }
    }
    // ELU
#pragma unroll
    for (int n = 0; n < 4; ++n) {
        a0[n] = a0[n] > 0.f ? a0[n] : (expf(a0[n]) - 1.f);
        a1[n] = a1[n] > 0.f ? a1[n] : (expf(a1[n]) - 1.f);
    }

    // LN1 (4 independent full-wave butterflies; channel pair per lane)
    float ha0 = ln1g[c0], ha1 = ln1g[c1], hb0 = ln1b[c0], hb1 = ln1b[c1];
    float tt[4], qq[4];
#pragma unroll
    for (int n = 0; n < 4; ++n) tt[n] = a0[n] + a1[n];
#pragma unroll
    for (int m = 1; m < 64; m <<= 1)
#pragma unroll
        for (int n = 0; n < 4; ++n) tt[n] += __shfl_xor(tt[n], m);
#pragma unroll
    for (int n = 0; n < 4; ++n) {
        float mn = tt[n] * (1.0f / 128.0f);
        a0[n] -= mn; a1[n] -= mn;
        qq[n] = a0[n] * a0[n] + a1[n] * a1[n];
    }
#pragma unroll
    for (int m = 1; m < 64; m <<= 1)
#pragma unroll
        for (int n = 0; n < 4; ++n) qq[n] += __shfl_xor(qq[n], m);
#pragma unroll
    for (int n = 0; n < 4; ++n) {
        float rs = rsqrtf(qq[n] * (1.0f / 128.0f) + 1e-5f);
        xs[wave][n][c0] = a0[n] * rs * ha0 + hb0;
        xs[wave][n][c1] = a1[n] * rs * ha1 + hb1;
    }

    // head: lane = (node hn, class hc)
    int hn = lane >> 4, hc = lane & 15;
    float p = bo[hc];
#pragma unroll 16
    for (int k = 0; k < 128; ++k)
        p += xs[wave][hn][k] * Wo[k * 16 + hc];
    float ss = p * p;
#pragma unroll
    for (int m = 1; m < 16; m <<= 1) ss += __shfl_xor(ss, m);
    float rinv = 1.0f / fmaxf(sqrtf(ss), 1e-12f);
    out[(size_t)(node0 + hn) * 16 + hc] = p * rinv;
}

// ---------------- launch ----------------
extern "C" void kernel_launch(void* const* d_in, const int* in_sizes, int n_in,
                              void* d_out, int out_size, void* d_ws, size_t ws_size,
                              hipStream_t stream)
{
    const float* feat0 = (const float*)d_in[0];
    const float* feat1 = (const float*)d_in[1];
    const int*   src   = (const int*)d_in[2];
    const int*   dst   = (const int*)d_in[3];
    const float* W0    = (const float*)d_in[4];
    const float* b0    = (const float*)d_in[5];
    const float* W1    = (const float*)d_in[6];
    const float* b1    = (const float*)d_in[7];
    const float* ln0_g = (const float*)d_in[8];
    const float* ln0_b = (const float*)d_in[9];
    const float* ln1_g = (const float*)d_in[10];
    const float* ln1_b = (const float*)d_in[11];
    const float* Wp    = (const float*)d_in[12];
    const float* bp    = (const float*)d_in[13];
    const float* Wo    = (const float*)d_in[14];
    const float* bo    = (const float*)d_in[15];
    float* out = (float*)d_out;

    char* ws = (char*)d_ws;
    // workspace layout (bytes)
    __half*         gbuf = (__half*)(ws + 0);           // 9 * (NN+1)*128*2 = 92,162,304
    float*          ns   = (float*)(ws + 92162304);     // 160,000
    float*          nsd  = (float*)(ws + 92322304);     // 160,000
    float*          rns  = (float*)(ws + 92482304);     // 160,000
    unsigned*       odeg = (unsigned*)(ws + 92642304);  // 160,000
    unsigned*       cnt  = (unsigned*)(ws + 92802304);  // 160,000 (= in_deg after degbucket)
    unsigned short* csr  = (unsigned short*)(ws + 92962304); // NN*64*2 = 5,120,000
    // total ~98.1 MB

    // zero degree counters (odeg + cnt contiguous)
    hipMemsetAsync(odeg, 0, 320000, stream);

    degbucket_kernel<<<(NE + 255) / 256, 256, 0, stream>>>(src, dst, odeg, cnt, csr, NE);
    norm_kernel<<<(NN + 255) / 256, 256, 0, stream>>>(odeg, cnt, ns, nsd, rns, NN);
    zero_pad_kernel<<<5, 256, 0, stream>>>(gbuf);

    proj_kernel<<<NT0 / 8, 128, 8 * 256 * 4, stream>>>(feat0, W0, b0, ns, gbuf, 0, 256);
    proj_kernel<<<NT0 / 8, 128, 8 * 128 * 4, stream>>>(feat1, W1, b1, ns, gbuf, NT0, 128);

    // 8 hops: g_{k} -> g_{k+1}
    for (int h = 0; h < NHOPS; ++h) {
        hop_kernel<<<NN / 4, 256, 0, stream>>>(gbuf + (size_t)h * GSTRIDE,
                                               gbuf + (size_t)(h + 1) * GSTRIDE,
                                               cnt, csr, nsd);
    }

    fin_kernel<<<NN / 16, 256, 0, stream>>>(gbuf, rns, ln0_g, ln0_b, ln1_g, ln1_b,
                                            Wp, bp, Wo, bo, out);
}

// Round 8
// 384.981 us; speedup vs baseline: 1.0584x; 1.0584x over previous
//
#include <hip/hip_runtime.h>
#include <hip/hip_fp16.h>
#include <math.h>

#define NN     40000
#define NT0    20000
#define NE     640000
#define NHOPS  8
#define RCAP   64
#define NSLICE 8
#define SLICEN (NN / NSLICE)                  // 5000 nodes per XCD slice
#define GSTRIDE ((size_t)(NN + 1) * 128)      // elems per g buffer (row NN = dummy zero)

// ---------------- fill csr with dummy node (XCD-sliced) ----------------
// csr viewed as uint (2 ushorts). Per slice: 5000*64/2 = 160000 uints.
__global__ void fill_kernel(unsigned* __restrict__ csr2)
{
    int slice = blockIdx.x & 7;
    int pb = blockIdx.x >> 3;                 // 0..255
    int idx = pb * 256 + threadIdx.x;         // 0..65535
    unsigned* base = csr2 + slice * (SLICEN * RCAP / 2);
    const unsigned pat = (40000u << 16) | 40000u;   // NN | NN
    for (int u = idx; u < SLICEN * RCAP / 2; u += 65536) base[u] = pat;
}

// ---------------- fused degree count + bucket, XCD-sliced ----------------
// slice = blockIdx&7 commits only nodes in [slice*5000, slice*5000+5000)
__global__ void degbucket_kernel(const int* __restrict__ src, const int* __restrict__ dst,
                                 unsigned* __restrict__ out_deg, unsigned* __restrict__ cnt,
                                 unsigned short* __restrict__ csr, int E)
{
    int slice = blockIdx.x & 7;
    int lo = slice * SLICEN, hi = lo + SLICEN;
    int pb = blockIdx.x >> 3;
    int start = pb * 256 + threadIdx.x;
    for (int e = start; e < E; e += 65536) {
        int s = src[e], d = dst[e];
        if (s >= lo && s < hi) atomicAdd(&out_deg[s], 1u);
        if (d >= lo && d < hi) {
            unsigned p = atomicAdd(&cnt[d], 1u);
            if (p < RCAP) csr[(d << 6) + (int)p] = (unsigned short)s;
        }
    }
}

// ---------------- norms: ns = out_deg^-1/2, nsd = ns*nd, rns = sqrt(out_deg) ------
__global__ void norm_kernel(const unsigned* __restrict__ out_deg, const unsigned* __restrict__ in_deg,
                            float* __restrict__ ns, float* __restrict__ nsd,
                            float* __restrict__ rns, int n)
{
    int i = blockIdx.x * blockDim.x + threadIdx.x;
    if (i >= n) return;
    float od = fmaxf((float)out_deg[i], 1.0f);
    float s = rsqrtf(od);
    float d = rsqrtf(fmaxf((float)in_deg[i], 1.0f));
    ns[i] = s; nsd[i] = s * d; rns[i] = sqrtf(od);
}

// ---------------- zero the dummy row (NN) of all 9 g buffers ----------------
__global__ void zero_pad_kernel(__half* __restrict__ g)
{
    int t = blockIdx.x * blockDim.x + threadIdx.x;
    int k = t >> 7, j = t & 127;
    if (k < 9) g[(size_t)k * GSTRIDE + ((size_t)NN << 7) + j] = __float2half(0.f);
}

// ---------------- input projection -> g0 = h*ns (fp16, full-row layout) ----------
__global__ void proj_kernel(const float* __restrict__ feat, const float* __restrict__ W,
                            const float* __restrict__ b, const float* __restrict__ ns,
                            __half* __restrict__ g0, int row0, int K)
{
    int j = threadIdx.x;
    int rbase = blockIdx.x * 8;
    extern __shared__ float xsm[];       // [8][K]
    for (int r = 0; r < 8; ++r)
        for (int k = j; k < K; k += 128)
            xsm[r * K + k] = feat[(size_t)(rbase + r) * K + k];
    __syncthreads();
    float bj = b[j];
    float acc[8];
#pragma unroll
    for (int r = 0; r < 8; ++r) acc[r] = bj;
    for (int k = 0; k < K; ++k) {
        float w = W[k * 128 + j];
#pragma unroll
        for (int r = 0; r < 8; ++r) acc[r] += xsm[r * K + k] * w;
    }
    for (int r = 0; r < 8; ++r) {
        int row = row0 + rbase + r;
        g0[((size_t)row << 7) + j] = __float2half(acc[r] * ns[row]);
    }
}

// ---------------- one hop: wave per node; 4 subgroups x 16 lanes x 16B; 16 edges/iter
__global__ __launch_bounds__(256) void hop_kernel(
    const __half* __restrict__ gc, __half* __restrict__ gn,
    const unsigned* __restrict__ ideg, const unsigned short* __restrict__ csr,
    const float* __restrict__ nsd)
{
    int node = blockIdx.x * 4 + (threadIdx.x >> 6);
    int lane = threadIdx.x & 63;
    int sub = lane >> 4;
    int ch8 = lane & 15;
    int dd = (int)ideg[node];
    int len = dd > RCAP ? RCAP : ((dd + 15) & ~15);
    int beg = node << 6;
    int end = beg + len;

    float a[8] = {0.f, 0.f, 0.f, 0.f, 0.f, 0.f, 0.f, 0.f};
    for (int base = beg; base < end; base += 16) {
        int i = base + sub;
        int s0 = (int)csr[i];
        int s1 = (int)csr[i + 4];
        int s2 = (int)csr[i + 8];
        int s3 = (int)csr[i + 12];
        int4 v0 = *(const int4*)(gc + ((size_t)s0 << 7) + (ch8 << 3));
        int4 v1 = *(const int4*)(gc + ((size_t)s1 << 7) + (ch8 << 3));
        int4 v2 = *(const int4*)(gc + ((size_t)s2 << 7) + (ch8 << 3));
        int4 v3 = *(const int4*)(gc + ((size_t)s3 << 7) + (ch8 << 3));
        float2 f;
        f = __half22float2(*(__half2*)&v0.x); a[0] += f.x; a[1] += f.y;
        f = __half22float2(*(__half2*)&v0.y); a[2] += f.x; a[3] += f.y;
        f = __half22float2(*(__half2*)&v0.z); a[4] += f.x; a[5] += f.y;
        f = __half22float2(*(__half2*)&v0.w); a[6] += f.x; a[7] += f.y;
        f = __half22float2(*(__half2*)&v1.x); a[0] += f.x; a[1] += f.y;
        f = __half22float2(*(__half2*)&v1.y); a[2] += f.x; a[3] += f.y;
        f = __half22float2(*(__half2*)&v1.z); a[4] += f.x; a[5] += f.y;
        f = __half22float2(*(__half2*)&v1.w); a[6] += f.x; a[7] += f.y;
        f = __half22float2(*(__half2*)&v2.x); a[0] += f.x; a[1] += f.y;
        f = __half22float2(*(__half2*)&v2.y); a[2] += f.x; a[3] += f.y;
        f = __half22float2(*(__half2*)&v2.z); a[4] += f.x; a[5] += f.y;
        f = __half22float2(*(__half2*)&v2.w); a[6] += f.x; a[7] += f.y;
        f = __half22float2(*(__half2*)&v3.x); a[0] += f.x; a[1] += f.y;
        f = __half22float2(*(__half2*)&v3.y); a[2] += f.x; a[3] += f.y;
        f = __half22float2(*(__half2*)&v3.z); a[4] += f.x; a[5] += f.y;
        f = __half22float2(*(__half2*)&v3.w); a[6] += f.x; a[7] += f.y;
    }
#pragma unroll
    for (int j = 0; j < 8; ++j) {
        a[j] += __shfl_xor(a[j], 16);
        a[j] += __shfl_xor(a[j], 32);
    }
    if (sub == 0) {
        float k = nsd[node];
        __half2 h0 = __float22half2_rn(make_float2(a[0] * k, a[1] * k));
        __half2 h1 = __float22half2_rn(make_float2(a[2] * k, a[3] * k));
        __half2 h2 = __float22half2_rn(make_float2(a[4] * k, a[5] * k));
        __half2 h3 = __float22half2_rn(make_float2(a[6] * k, a[7] * k));
        int4 w;
        w.x = *(int*)&h0; w.y = *(int*)&h1; w.z = *(int*)&h2; w.w = *(int*)&h3;
        *(int4*)(gn + ((size_t)node << 7) + (ch8 << 3)) = w;
    }
}

// ---------------- gsum: x = (sum_k g_k) * rns / 9, fp16 out (pure streaming) ------
__global__ __launch_bounds__(256) void gsum_kernel(
    const __half* __restrict__ g, const float* __restrict__ rns,
    __half* __restrict__ x)
{
    int c = blockIdx.x * 256 + threadIdx.x;   // chunk id, 16B each; grid covers exactly
    int node = c >> 4, ch0 = (c & 15) << 3;
    float s8[8] = {0,0,0,0,0,0,0,0};
#pragma unroll
    for (int k = 0; k < 9; ++k) {
        int4 v = *(const int4*)(g + (size_t)k * GSTRIDE + ((size_t)node << 7) + ch0);
        float2 f;
        f = __half22float2(*(__half2*)&v.x); s8[0] += f.x; s8[1] += f.y;
        f = __half22float2(*(__half2*)&v.y); s8[2] += f.x; s8[3] += f.y;
        f = __half22float2(*(__half2*)&v.z); s8[4] += f.x; s8[5] += f.y;
        f = __half22float2(*(__half2*)&v.w); s8[6] += f.x; s8[7] += f.y;
    }
    float sc = rns[node] * (1.0f / 9.0f);
    __half2 h0 = __float22half2_rn(make_float2(s8[0] * sc, s8[1] * sc));
    __half2 h1 = __float22half2_rn(make_float2(s8[2] * sc, s8[3] * sc));
    __half2 h2 = __float22half2_rn(make_float2(s8[4] * sc, s8[5] * sc));
    __half2 h3 = __float22half2_rn(make_float2(s8[6] * sc, s8[7] * sc));
    int4 w;
    w.x = *(int*)&h0; w.y = *(int*)&h1; w.z = *(int*)&h2; w.w = *(int*)&h3;
    *(int4*)(x + ((size_t)node << 7) + ch0) = w;
}

// ---------------- mlp: LN0, Wp+ELU, LN1, Wo, L2 norm ----------------
__global__ __launch_bounds__(256) void mlp_kernel(
    const __half* __restrict__ x,
    const float* __restrict__ ln0g, const float* __restrict__ ln0b,
    const float* __restrict__ ln1g, const float* __restrict__ ln1b,
    const float* __restrict__ Wp, const float* __restrict__ bp,
    const float* __restrict__ Wo, const float* __restrict__ bo,
    float* __restrict__ out)
{
    __shared__ float xs[4][4][132];
    int wave = threadIdx.x >> 6, lane = threadIdx.x & 63;
    int sub = lane >> 4, ck = lane & 15;
    int node0 = blockIdx.x * 16 + wave * 4;
    int node = node0 + sub;
    int ch0 = ck << 3;

    float s8[8];
    {
        int4 v = *(const int4*)(x + ((size_t)node << 7) + ch0);
        float2 f;
        f = __half22float2(*(__half2*)&v.x); s8[0] = f.x; s8[1] = f.y;
        f = __half22float2(*(__half2*)&v.y); s8[2] = f.x; s8[3] = f.y;
        f = __half22float2(*(__half2*)&v.z); s8[4] = f.x; s8[5] = f.y;
        f = __half22float2(*(__half2*)&v.w); s8[6] = f.x; s8[7] = f.y;
    }

    // LN0: reduce within 16-lane node group
    float t = 0.f;
#pragma unroll
    for (int i = 0; i < 8; ++i) t += s8[i];
#pragma unroll
    for (int m = 1; m < 16; m <<= 1) t += __shfl_xor(t, m);
    float mean = t * (1.0f / 128.0f);
    float q = 0.f;
#pragma unroll
    for (int i = 0; i < 8; ++i) { s8[i] -= mean; q += s8[i] * s8[i]; }
#pragma unroll
    for (int m = 1; m < 16; m <<= 1) q += __shfl_xor(q, m);
    float rstd = rsqrtf(q * (1.0f / 128.0f) + 1e-5f);
    float4 ga = *(const float4*)(ln0g + ch0);
    float4 gA = *(const float4*)(ln0g + ch0 + 4);
    float4 ba = *(const float4*)(ln0b + ch0);
    float4 bA = *(const float4*)(ln0b + ch0 + 4);
    xs[wave][sub][ch0 + 0] = s8[0] * rstd * ga.x + ba.x;
    xs[wave][sub][ch0 + 1] = s8[1] * rstd * ga.y + ba.y;
    xs[wave][sub][ch0 + 2] = s8[2] * rstd * ga.z + ba.z;
    xs[wave][sub][ch0 + 3] = s8[3] * rstd * ga.w + ba.w;
    xs[wave][sub][ch0 + 4] = s8[4] * rstd * gA.x + bA.x;
    xs[wave][sub][ch0 + 5] = s8[5] * rstd * gA.y + bA.y;
    xs[wave][sub][ch0 + 6] = s8[6] * rstd * gA.z + bA.z;
    xs[wave][sub][ch0 + 7] = s8[7] * rstd * gA.w + bA.w;

    // GEMV Wp (lane owns output cols c0,c1 for all 4 nodes of its wave)
    int c0 = lane * 2, c1 = c0 + 1;
    float a0[4], a1[4];
    float bp0 = bp[c0], bp1 = bp[c1];
#pragma unroll
    for (int n = 0; n < 4; ++n) { a0[n] = bp0; a1[n] = bp1; }
#pragma unroll 16
    for (int k = 0; k < 128; ++k) {
        float2 w = *(const float2*)(Wp + k * 128 + c0);
#pragma unroll
        for (int n = 0; n < 4; ++n) {
            float xk = xs[wave][n][k];
            a0[n] += xk * w.x; a1[n] += xk * w.y;
        }
    }
#pragma unroll
    for (int n = 0; n < 4; ++n) {
        a0[n] = a0[n] > 0.f ? a0[n] : (expf(a0[n]) - 1.f);
        a1[n] = a1[n] > 0.f ? a1[n] : (expf(a1[n]) - 1.f);
    }

    // LN1 (4 independent full-wave butterflies; channel pair per lane)
    float ha0 = ln1g[c0], ha1 = ln1g[c1], hb0 = ln1b[c0], hb1 = ln1b[c1];
    float tt[4], qq[4];
#pragma unroll
    for (int n = 0; n < 4; ++n) tt[n] = a0[n] + a1[n];
#pragma unroll
    for (int m = 1; m < 64; m <<= 1)
#pragma unroll
        for (int n = 0; n < 4; ++n) tt[n] += __shfl_xor(tt[n], m);
#pragma unroll
    for (int n = 0; n < 4; ++n) {
        float mn = tt[n] * (1.0f / 128.0f);
        a0[n] -= mn; a1[n] -= mn;
        qq[n] = a0[n] * a0[n] + a1[n] * a1[n];
    }
#pragma unroll
    for (int m = 1; m < 64; m <<= 1)
#pragma unroll
        for (int n = 0; n < 4; ++n) qq[n] += __shfl_xor(qq[n], m);
#pragma unroll
    for (int n = 0; n < 4; ++n) {
        float rs = rsqrtf(qq[n] * (1.0f / 128.0f) + 1e-5f);
        xs[wave][n][c0] = a0[n] * rs * ha0 + hb0;
        xs[wave][n][c1] = a1[n] * rs * ha1 + hb1;
    }

    // head: lane = (node hn, class hc)
    int hn = lane >> 4, hc = lane & 15;
    float p = bo[hc];
#pragma unroll 16
    for (int k = 0; k < 128; ++k)
        p += xs[wave][hn][k] * Wo[k * 16 + hc];
    float ss = p * p;
#pragma unroll
    for (int m = 1; m < 16; m <<= 1) ss += __shfl_xor(ss, m);
    float rinv = 1.0f / fmaxf(sqrtf(ss), 1e-12f);
    out[(size_t)(node0 + hn) * 16 + hc] = p * rinv;
}

// ---------------- launch ----------------
extern "C" void kernel_launch(void* const* d_in, const int* in_sizes, int n_in,
                              void* d_out, int out_size, void* d_ws, size_t ws_size,
                              hipStream_t stream)
{
    const float* feat0 = (const float*)d_in[0];
    const float* feat1 = (const float*)d_in[1];
    const int*   src   = (const int*)d_in[2];
    const int*   dst   = (const int*)d_in[3];
    const float* W0    = (const float*)d_in[4];
    const float* b0    = (const float*)d_in[5];
    const float* W1    = (const float*)d_in[6];
    const float* b1    = (const float*)d_in[7];
    const float* ln0_g = (const float*)d_in[8];
    const float* ln0_b = (const float*)d_in[9];
    const float* ln1_g = (const float*)d_in[10];
    const float* ln1_b = (const float*)d_in[11];
    const float* Wp    = (const float*)d_in[12];
    const float* bp    = (const float*)d_in[13];
    const float* Wo    = (const float*)d_in[14];
    const float* bo    = (const float*)d_in[15];
    float* out = (float*)d_out;

    char* ws = (char*)d_ws;
    // workspace layout (bytes) — x overlays the csr region (csr dead after hops)
    __half*         gbuf = (__half*)(ws + 0);           // 92,162,304
    float*          ns   = (float*)(ws + 92162304);     // 160,000
    float*          nsd  = (float*)(ws + 92322304);     // 160,000
    float*          rns  = (float*)(ws + 92482304);     // 160,000
    unsigned*       odeg = (unsigned*)(ws + 92642304);  // 160,000
    unsigned*       cnt  = (unsigned*)(ws + 92802304);  // 160,000
    unsigned short* csr  = (unsigned short*)(ws + 92962304); // 5,120,000
    __half*         xbuf = (__half*)(ws + 92962304);    // 10,240,000 (overlay)
    // total ~103.2 MB

    hipMemsetAsync(odeg, 0, 320000, stream);

    fill_kernel<<<2048, 256, 0, stream>>>((unsigned*)csr);
    degbucket_kernel<<<2048, 256, 0, stream>>>(src, dst, odeg, cnt, csr, NE);
    norm_kernel<<<(NN + 255) / 256, 256, 0, stream>>>(odeg, cnt, ns, nsd, rns, NN);
    zero_pad_kernel<<<5, 256, 0, stream>>>(gbuf);

    proj_kernel<<<NT0 / 8, 128, 8 * 256 * 4, stream>>>(feat0, W0, b0, ns, gbuf, 0, 256);
    proj_kernel<<<NT0 / 8, 128, 8 * 128 * 4, stream>>>(feat1, W1, b1, ns, gbuf, NT0, 128);

    for (int h = 0; h < NHOPS; ++h) {
        hop_kernel<<<NN / 4, 256, 0, stream>>>(gbuf + (size_t)h * GSTRIDE,
                                               gbuf + (size_t)(h + 1) * GSTRIDE,
                                               cnt, csr, nsd);
    }

    gsum_kernel<<<2500, 256, 0, stream>>>(gbuf, rns, xbuf);
    mlp_kernel<<<NN / 16, 256, 0, stream>>>(xbuf, ln0_g, ln0_b, ln1_g, ln1_b,
                                            Wp, bp, Wo, bo, out);
}

// Round 9
// 331.864 us; speedup vs baseline: 1.2278x; 1.1601x over previous
//
#include <hip/hip_runtime.h>
#include <hip/hip_fp16.h>
#include <math.h>

#define NN     40000
#define NT0    20000
#define NE     640000
#define NHOPS  8
#define RCAP   64
#define NSLICE 8
#define SLICEN (NN / NSLICE)                  // 5000 nodes per XCD slice
#define GSTRIDE ((size_t)(NN + 1) * 128)      // elems per g buffer (row NN = dummy zero)

typedef _Float16 f16x8 __attribute__((ext_vector_type(8)));
typedef float    f32x4 __attribute__((ext_vector_type(4)));

// ---------------- fill csr with dummy node (XCD-sliced) ----------------
__global__ void fill_kernel(unsigned* __restrict__ csr2)
{
    int slice = blockIdx.x & 7;
    int pb = blockIdx.x >> 3;
    int idx = pb * 256 + threadIdx.x;
    unsigned* base = csr2 + slice * (SLICEN * RCAP / 2);
    const unsigned pat = (40000u << 16) | 40000u;
    for (int u = idx; u < SLICEN * RCAP / 2; u += 65536) base[u] = pat;
}

// ---------------- fused degree count + bucket, XCD-sliced ----------------
__global__ void degbucket_kernel(const int* __restrict__ src, const int* __restrict__ dst,
                                 unsigned* __restrict__ out_deg, unsigned* __restrict__ cnt,
                                 unsigned short* __restrict__ csr, int E)
{
    int slice = blockIdx.x & 7;
    int lo = slice * SLICEN, hi = lo + SLICEN;
    int pb = blockIdx.x >> 3;
    int start = pb * 256 + threadIdx.x;
    for (int e = start; e < E; e += 65536) {
        int s = src[e], d = dst[e];
        if (s >= lo && s < hi) atomicAdd(&out_deg[s], 1u);
        if (d >= lo && d < hi) {
            unsigned p = atomicAdd(&cnt[d], 1u);
            if (p < RCAP) csr[(d << 6) + (int)p] = (unsigned short)s;
        }
    }
}

// ---------------- norms ----------------
__global__ void norm_kernel(const unsigned* __restrict__ out_deg, const unsigned* __restrict__ in_deg,
                            float* __restrict__ ns, float* __restrict__ nsd,
                            float* __restrict__ rns, int n)
{
    int i = blockIdx.x * blockDim.x + threadIdx.x;
    if (i >= n) return;
    float od = fmaxf((float)out_deg[i], 1.0f);
    float s = rsqrtf(od);
    float d = rsqrtf(fmaxf((float)in_deg[i], 1.0f));
    ns[i] = s; nsd[i] = s * d; rns[i] = sqrtf(od);
}

// ---------------- zero the dummy row (NN) of all 9 g buffers ----------------
__global__ void zero_pad_kernel(__half* __restrict__ g)
{
    int t = blockIdx.x * blockDim.x + threadIdx.x;
    int k = t >> 7, j = t & 127;
    if (k < 9) g[(size_t)k * GSTRIDE + ((size_t)NN << 7) + j] = __float2half(0.f);
}

// ---------------- W[K][128] f32 -> WT[128][K] fp16 (tiled transpose) ----------
__global__ __launch_bounds__(256) void wtrans_kernel(const float* __restrict__ W,
                                                     _Float16* __restrict__ WT, int K)
{
    __shared__ float t[32][33];
    int bk = blockIdx.x * 32;
    int bn = blockIdx.y * 32;
    int tx = threadIdx.x & 31, ty4 = (threadIdx.x >> 5) * 4;
#pragma unroll
    for (int i = 0; i < 4; ++i)
        t[ty4 + i][tx] = W[(size_t)(bk + ty4 + i) * 128 + bn + tx];
    __syncthreads();
#pragma unroll
    for (int i = 0; i < 4; ++i)
        WT[(size_t)(bn + ty4 + i) * K + bk + tx] = (_Float16)t[tx][ty4 + i];
}

// ---------------- MFMA projection: g0[row0+r] = fp16((feat @ W + b) * ns) --------
// block = 256 thr = 4 waves; wave handles 16 rows x 128 cols; K steps of 32.
template<int K>
__global__ __launch_bounds__(256) void projmm_kernel(
    const float* __restrict__ feat, const _Float16* __restrict__ WT,  // WT[128][K]
    const float* __restrict__ b, const float* __restrict__ ns,
    __half* __restrict__ g0, int row0, int M)
{
    constexpr int LDB = K + 8;
    __shared__ _Float16 BT[128 * LDB];
    int tid = threadIdx.x;
    // stage WT -> LDS (coalesced b128 copy)
    for (int idx = tid * 8; idx < 128 * K; idx += 256 * 8) {
        int n = idx / K, k = idx % K;
        *(f16x8*)(&BT[n * LDB + k]) = *(const f16x8*)(&WT[n * K + k]);
    }
    __syncthreads();

    int wave = tid >> 6, lane = tid & 63;
    int rb = blockIdx.x * 64 + wave * 16;       // local row base
    int lr = lane & 15, lk = lane >> 4;

    f32x4 acc[8] = {};                           // 8 n-tiles of 16 cols

    int arow = rb + lr; if (arow >= M) arow = M - 1;   // clamp reads (writes guarded)
    const float* afp = feat + (size_t)arow * K;

    for (int k0 = 0; k0 < K; k0 += 32) {
        float4 fa = *(const float4*)(afp + k0 + lk * 8);
        float4 fb = *(const float4*)(afp + k0 + lk * 8 + 4);
        f16x8 a;
        a[0] = (_Float16)fa.x; a[1] = (_Float16)fa.y;
        a[2] = (_Float16)fa.z; a[3] = (_Float16)fa.w;
        a[4] = (_Float16)fb.x; a[5] = (_Float16)fb.y;
        a[6] = (_Float16)fb.z; a[7] = (_Float16)fb.w;
#pragma unroll
        for (int t = 0; t < 8; ++t) {
            f16x8 bf = *(const f16x8*)(&BT[(t * 16 + lr) * LDB + k0 + lk * 8]);
            acc[t] = __builtin_amdgcn_mfma_f32_16x16x32_f16(a, bf, acc[t], 0, 0, 0);
        }
    }

    float bv[8];
#pragma unroll
    for (int t = 0; t < 8; ++t) bv[t] = b[t * 16 + lr];
#pragma unroll
    for (int reg = 0; reg < 4; ++reg) {
        int r = rb + lk * 4 + reg;               // D row = (lane>>4)*4 + reg
        if (r < M) {
            float s = ns[row0 + r];
            size_t base = ((size_t)(row0 + r)) << 7;
#pragma unroll
            for (int t = 0; t < 8; ++t)
                g0[base + t * 16 + lr] = __float2half((acc[t][reg] + bv[t]) * s);
        }
    }
}

// ---------------- one hop: wave per node; 4 subgroups x 16 lanes x 16B ----------
__global__ __launch_bounds__(256) void hop_kernel(
    const __half* __restrict__ gc, __half* __restrict__ gn,
    const unsigned* __restrict__ ideg, const unsigned short* __restrict__ csr,
    const float* __restrict__ nsd)
{
    int node = blockIdx.x * 4 + (threadIdx.x >> 6);
    int lane = threadIdx.x & 63;
    int sub = lane >> 4;
    int ch8 = lane & 15;
    int dd = (int)ideg[node];
    int len = dd > RCAP ? RCAP : ((dd + 15) & ~15);
    int beg = node << 6;
    int end = beg + len;

    float a[8] = {0.f, 0.f, 0.f, 0.f, 0.f, 0.f, 0.f, 0.f};
    for (int base = beg; base < end; base += 16) {
        int i = base + sub;
        int s0 = (int)csr[i];
        int s1 = (int)csr[i + 4];
        int s2 = (int)csr[i + 8];
        int s3 = (int)csr[i + 12];
        int4 v0 = *(const int4*)(gc + ((size_t)s0 << 7) + (ch8 << 3));
        int4 v1 = *(const int4*)(gc + ((size_t)s1 << 7) + (ch8 << 3));
        int4 v2 = *(const int4*)(gc + ((size_t)s2 << 7) + (ch8 << 3));
        int4 v3 = *(const int4*)(gc + ((size_t)s3 << 7) + (ch8 << 3));
        float2 f;
        f = __half22float2(*(__half2*)&v0.x); a[0] += f.x; a[1] += f.y;
        f = __half22float2(*(__half2*)&v0.y); a[2] += f.x; a[3] += f.y;
        f = __half22float2(*(__half2*)&v0.z); a[4] += f.x; a[5] += f.y;
        f = __half22float2(*(__half2*)&v0.w); a[6] += f.x; a[7] += f.y;
        f = __half22float2(*(__half2*)&v1.x); a[0] += f.x; a[1] += f.y;
        f = __half22float2(*(__half2*)&v1.y); a[2] += f.x; a[3] += f.y;
        f = __half22float2(*(__half2*)&v1.z); a[4] += f.x; a[5] += f.y;
        f = __half22float2(*(__half2*)&v1.w); a[6] += f.x; a[7] += f.y;
        f = __half22float2(*(__half2*)&v2.x); a[0] += f.x; a[1] += f.y;
        f = __half22float2(*(__half2*)&v2.y); a[2] += f.x; a[3] += f.y;
        f = __half22float2(*(__half2*)&v2.z); a[4] += f.x; a[5] += f.y;
        f = __half22float2(*(__half2*)&v2.w); a[6] += f.x; a[7] += f.y;
        f = __half22float2(*(__half2*)&v3.x); a[0] += f.x; a[1] += f.y;
        f = __half22float2(*(__half2*)&v3.y); a[2] += f.x; a[3] += f.y;
        f = __half22float2(*(__half2*)&v3.z); a[4] += f.x; a[5] += f.y;
        f = __half22float2(*(__half2*)&v3.w); a[6] += f.x; a[7] += f.y;
    }
#pragma unroll
    for (int j = 0; j < 8; ++j) {
        a[j] += __shfl_xor(a[j], 16);
        a[j] += __shfl_xor(a[j], 32);
    }
    if (sub == 0) {
        float k = nsd[node];
        __half2 h0 = __float22half2_rn(make_float2(a[0] * k, a[1] * k));
        __half2 h1 = __float22half2_rn(make_float2(a[2] * k, a[3] * k));
        __half2 h2 = __float22half2_rn(make_float2(a[4] * k, a[5] * k));
        __half2 h3 = __float22half2_rn(make_float2(a[6] * k, a[7] * k));
        int4 w;
        w.x = *(int*)&h0; w.y = *(int*)&h1; w.z = *(int*)&h2; w.w = *(int*)&h3;
        *(int4*)(gn + ((size_t)node << 7) + (ch8 << 3)) = w;
    }
}

// ---------------- gsum: x = (sum_k g_k) * rns / 9, fp16 out ----------------
__global__ __launch_bounds__(256) void gsum_kernel(
    const __half* __restrict__ g, const float* __restrict__ rns,
    __half* __restrict__ x)
{
    int c = blockIdx.x * 256 + threadIdx.x;
    int node = c >> 4, ch0 = (c & 15) << 3;
    float s8[8] = {0,0,0,0,0,0,0,0};
#pragma unroll
    for (int k = 0; k < 9; ++k) {
        int4 v = *(const int4*)(g + (size_t)k * GSTRIDE + ((size_t)node << 7) + ch0);
        float2 f;
        f = __half22float2(*(__half2*)&v.x); s8[0] += f.x; s8[1] += f.y;
        f = __half22float2(*(__half2*)&v.y); s8[2] += f.x; s8[3] += f.y;
        f = __half22float2(*(__half2*)&v.z); s8[4] += f.x; s8[5] += f.y;
        f = __half22float2(*(__half2*)&v.w); s8[6] += f.x; s8[7] += f.y;
    }
    float sc = rns[node] * (1.0f / 9.0f);
    __half2 h0 = __float22half2_rn(make_float2(s8[0] * sc, s8[1] * sc));
    __half2 h1 = __float22half2_rn(make_float2(s8[2] * sc, s8[3] * sc));
    __half2 h2 = __float22half2_rn(make_float2(s8[4] * sc, s8[5] * sc));
    __half2 h3 = __float22half2_rn(make_float2(s8[6] * sc, s8[7] * sc));
    int4 w;
    w.x = *(int*)&h0; w.y = *(int*)&h1; w.z = *(int*)&h2; w.w = *(int*)&h3;
    *(int4*)(x + ((size_t)node << 7) + ch0) = w;
}

// ---------------- mlp: LN0, Wp+ELU, LN1, Wo, L2 norm ----------------
__global__ __launch_bounds__(256) void mlp_kernel(
    const __half* __restrict__ x,
    const float* __restrict__ ln0g, const float* __restrict__ ln0b,
    const float* __restrict__ ln1g, const float* __restrict__ ln1b,
    const float* __restrict__ Wp, const float* __restrict__ bp,
    const float* __restrict__ Wo, const float* __restrict__ bo,
    float* __restrict__ out)
{
    __shared__ float xs[4][4][132];
    int wave = threadIdx.x >> 6, lane = threadIdx.x & 63;
    int sub = lane >> 4, ck = lane & 15;
    int node0 = blockIdx.x * 16 + wave * 4;
    int node = node0 + sub;
    int ch0 = ck << 3;

    float s8[8];
    {
        int4 v = *(const int4*)(x + ((size_t)node << 7) + ch0);
        float2 f;
        f = __half22float2(*(__half2*)&v.x); s8[0] = f.x; s8[1] = f.y;
        f = __half22float2(*(__half2*)&v.y); s8[2] = f.x; s8[3] = f.y;
        f = __half22float2(*(__half2*)&v.z); s8[4] = f.x; s8[5] = f.y;
        f = __half22float2(*(__half2*)&v.w); s8[6] = f.x; s8[7] = f.y;
    }

    // LN0 within 16-lane node group
    float t = 0.f;
#pragma unroll
    for (int i = 0; i < 8; ++i) t += s8[i];
#pragma unroll
    for (int m = 1; m < 16; m <<= 1) t += __shfl_xor(t, m);
    float mean = t * (1.0f / 128.0f);
    float q = 0.f;
#pragma unroll
    for (int i = 0; i < 8; ++i) { s8[i] -= mean; q += s8[i] * s8[i]; }
#pragma unroll
    for (int m = 1; m < 16; m <<= 1) q += __shfl_xor(q, m);
    float rstd = rsqrtf(q * (1.0f / 128.0f) + 1e-5f);
    float4 ga = *(const float4*)(ln0g + ch0);
    float4 gA = *(const float4*)(ln0g + ch0 + 4);
    float4 ba = *(const float4*)(ln0b + ch0);
    float4 bA = *(const float4*)(ln0b + ch0 + 4);
    xs[wave][sub][ch0 + 0] = s8[0] * rstd * ga.x + ba.x;
    xs[wave][sub][ch0 + 1] = s8[1] * rstd * ga.y + ba.y;
    xs[wave][sub][ch0 + 2] = s8[2] * rstd * ga.z + ba.z;
    xs[wave][sub][ch0 + 3] = s8[3] * rstd * ga.w + ba.w;
    xs[wave][sub][ch0 + 4] = s8[4] * rstd * gA.x + bA.x;
    xs[wave][sub][ch0 + 5] = s8[5] * rstd * gA.y + bA.y;
    xs[wave][sub][ch0 + 6] = s8[6] * rstd * gA.z + bA.z;
    xs[wave][sub][ch0 + 7] = s8[7] * rstd * gA.w + bA.w;

    // GEMV Wp
    int c0 = lane * 2, c1 = c0 + 1;
    float a0[4], a1[4];
    float bp0 = bp[c0], bp1 = bp[c1];
#pragma unroll
    for (int n = 0; n < 4; ++n) { a0[n] = bp0; a1[n] = bp1; }
#pragma unroll 16
    for (int k = 0; k < 128; ++k) {
        float2 w = *(const float2*)(Wp + k * 128 + c0);
#pragma unroll
        for (int n = 0; n < 4; ++n) {
            float xk = xs[wave][n][k];
            a0[n] += xk * w.x; a1[n] += xk * w.y;
        }
    }
#pragma unroll
    for (int n = 0; n < 4; ++n) {
        a0[n] = a0[n] > 0.f ? a0[n] : (expf(a0[n]) - 1.f);
        a1[n] = a1[n] > 0.f ? a1[n] : (expf(a1[n]) - 1.f);
    }

    // LN1
    float ha0 = ln1g[c0], ha1 = ln1g[c1], hb0 = ln1b[c0], hb1 = ln1b[c1];
    float tt[4], qq[4];
#pragma unroll
    for (int n = 0; n < 4; ++n) tt[n] = a0[n] + a1[n];
#pragma unroll
    for (int m = 1; m < 64; m <<= 1)
#pragma unroll
        for (int n = 0; n < 4; ++n) tt[n] += __shfl_xor(tt[n], m);
#pragma unroll
    for (int n = 0; n < 4; ++n) {
        float mn = tt[n] * (1.0f / 128.0f);
        a0[n] -= mn; a1[n] -= mn;
        qq[n] = a0[n] * a0[n] + a1[n] * a1[n];
    }
#pragma unroll
    for (int m = 1; m < 64; m <<= 1)
#pragma unroll
        for (int n = 0; n < 4; ++n) qq[n] += __shfl_xor(qq[n], m);
#pragma unroll
    for (int n = 0; n < 4; ++n) {
        float rs = rsqrtf(qq[n] * (1.0f / 128.0f) + 1e-5f);
        xs[wave][n][c0] = a0[n] * rs * ha0 + hb0;
        xs[wave][n][c1] = a1[n] * rs * ha1 + hb1;
    }

    // head
    int hn = lane >> 4, hc = lane & 15;
    float p = bo[hc];
#pragma unroll 16
    for (int k = 0; k < 128; ++k)
        p += xs[wave][hn][k] * Wo[k * 16 + hc];
    float ss = p * p;
#pragma unroll
    for (int m = 1; m < 16; m <<= 1) ss += __shfl_xor(ss, m);
    float rinv = 1.0f / fmaxf(sqrtf(ss), 1e-12f);
    out[(size_t)(node0 + hn) * 16 + hc] = p * rinv;
}

// ---------------- launch ----------------
extern "C" void kernel_launch(void* const* d_in, const int* in_sizes, int n_in,
                              void* d_out, int out_size, void* d_ws, size_t ws_size,
                              hipStream_t stream)
{
    const float* feat0 = (const float*)d_in[0];
    const float* feat1 = (const float*)d_in[1];
    const int*   src   = (const int*)d_in[2];
    const int*   dst   = (const int*)d_in[3];
    const float* W0    = (const float*)d_in[4];
    const float* b0    = (const float*)d_in[5];
    const float* W1    = (const float*)d_in[6];
    const float* b1    = (const float*)d_in[7];
    const float* ln0_g = (const float*)d_in[8];
    const float* ln0_b = (const float*)d_in[9];
    const float* ln1_g = (const float*)d_in[10];
    const float* ln1_b = (const float*)d_in[11];
    const float* Wp    = (const float*)d_in[12];
    const float* bp    = (const float*)d_in[13];
    const float* Wo    = (const float*)d_in[14];
    const float* bo    = (const float*)d_in[15];
    float* out = (float*)d_out;

    char* ws = (char*)d_ws;
    // workspace layout (bytes) — xbuf overlays csr (csr dead after hops)
    __half*         gbuf = (__half*)(ws + 0);           // 92,162,304
    float*          ns   = (float*)(ws + 92162304);     // 160,000
    float*          nsd  = (float*)(ws + 92322304);     // 160,000
    float*          rns  = (float*)(ws + 92482304);     // 160,000
    unsigned*       odeg = (unsigned*)(ws + 92642304);  // 160,000
    unsigned*       cnt  = (unsigned*)(ws + 92802304);  // 160,000
    unsigned short* csr  = (unsigned short*)(ws + 92962304); // 5,120,000
    __half*         xbuf = (__half*)(ws + 92962304);    // 10,240,000 (overlay)
    _Float16*       WT0  = (_Float16*)(ws + 103202304); // 65,536
    _Float16*       WT1  = (_Float16*)(ws + 103267840); // 32,768
    // total ~103.3 MB

    hipMemsetAsync(odeg, 0, 320000, stream);

    wtrans_kernel<<<dim3(8, 4), 256, 0, stream>>>(W0, WT0, 256);
    wtrans_kernel<<<dim3(4, 4), 256, 0, stream>>>(W1, WT1, 128);

    fill_kernel<<<2048, 256, 0, stream>>>((unsigned*)csr);
    degbucket_kernel<<<2048, 256, 0, stream>>>(src, dst, odeg, cnt, csr, NE);
    norm_kernel<<<(NN + 255) / 256, 256, 0, stream>>>(odeg, cnt, ns, nsd, rns, NN);
    zero_pad_kernel<<<5, 256, 0, stream>>>(gbuf);

    projmm_kernel<256><<<(NT0 + 63) / 64, 256, 0, stream>>>(feat0, WT0, b0, ns, gbuf, 0, NT0);
    projmm_kernel<128><<<(NT0 + 63) / 64, 256, 0, stream>>>(feat1, WT1, b1, ns, gbuf, NT0, NT0);

    for (int h = 0; h < NHOPS; ++h) {
        hop_kernel<<<NN / 4, 256, 0, stream>>>(gbuf + (size_t)h * GSTRIDE,
                                               gbuf + (size_t)(h + 1) * GSTRIDE,
                                               cnt, csr, nsd);
    }

    gsum_kernel<<<2500, 256, 0, stream>>>(gbuf, rns, xbuf);
    mlp_kernel<<<NN / 16, 256, 0, stream>>>(xbuf, ln0_g, ln0_b, ln1_g, ln1_b,
                                            Wp, bp, Wo, bo, out);
}

// Round 10
// 297.065 us; speedup vs baseline: 1.3716x; 1.1171x over previous
//
#include <hip/hip_runtime.h>
#include <hip/hip_fp16.h>
#include <math.h>

#define NN     40000
#define NT0    20000
#define NE     640000
#define NHOPS  8
#define RCAP   64
#define NSLICE 8
#define SLICEN (NN / NSLICE)
#define GSTRIDE ((size_t)(NN + 1) * 128)

typedef _Float16 f16x8 __attribute__((ext_vector_type(8)));
typedef float    f32x4 __attribute__((ext_vector_type(4)));

// ---------------- fill csr with dummy node (XCD-sliced) ----------------
__global__ void fill_kernel(unsigned* __restrict__ csr2)
{
    int slice = blockIdx.x & 7;
    int pb = blockIdx.x >> 3;
    int idx = pb * 256 + threadIdx.x;
    unsigned* base = csr2 + slice * (SLICEN * RCAP / 2);
    const unsigned pat = (40000u << 16) | 40000u;
    for (int u = idx; u < SLICEN * RCAP / 2; u += 65536) base[u] = pat;
}

// ---------------- fused degree count + bucket, XCD-sliced ----------------
__global__ void degbucket_kernel(const int* __restrict__ src, const int* __restrict__ dst,
                                 unsigned* __restrict__ out_deg, unsigned* __restrict__ cnt,
                                 unsigned short* __restrict__ csr, int E)
{
    int slice = blockIdx.x & 7;
    int lo = slice * SLICEN, hi = lo + SLICEN;
    int pb = blockIdx.x >> 3;
    int start = pb * 256 + threadIdx.x;
    for (int e = start; e < E; e += 65536) {
        int s = src[e], d = dst[e];
        if (s >= lo && s < hi) atomicAdd(&out_deg[s], 1u);
        if (d >= lo && d < hi) {
            unsigned p = atomicAdd(&cnt[d], 1u);
            if (p < RCAP) csr[(d << 6) + (int)p] = (unsigned short)s;
        }
    }
}

// ---------------- norms ----------------
__global__ void norm_kernel(const unsigned* __restrict__ out_deg, const unsigned* __restrict__ in_deg,
                            float* __restrict__ ns, float* __restrict__ nsd,
                            float* __restrict__ rns, int n)
{
    int i = blockIdx.x * blockDim.x + threadIdx.x;
    if (i >= n) return;
    float od = fmaxf((float)out_deg[i], 1.0f);
    float s = rsqrtf(od);
    float d = rsqrtf(fmaxf((float)in_deg[i], 1.0f));
    ns[i] = s; nsd[i] = s * d; rns[i] = sqrtf(od);
}

// ---------------- zero the dummy row (NN) of all 9 g buffers ----------------
__global__ void zero_pad_kernel(__half* __restrict__ g)
{
    int t = blockIdx.x * blockDim.x + threadIdx.x;
    int k = t >> 7, j = t & 127;
    if (k < 9) g[(size_t)k * GSTRIDE + ((size_t)NN << 7) + j] = __float2half(0.f);
}

// ---------------- W[K][128] f32 -> WT[128][K] fp16 (tiled transpose) ----------
__global__ __launch_bounds__(256) void wtrans_kernel(const float* __restrict__ W,
                                                     _Float16* __restrict__ WT, int K)
{
    __shared__ float t[32][33];
    int bk = blockIdx.x * 32;
    int bn = blockIdx.y * 32;
    int tx = threadIdx.x & 31, ty4 = (threadIdx.x >> 5) * 4;
#pragma unroll
    for (int i = 0; i < 4; ++i)
        t[ty4 + i][tx] = W[(size_t)(bk + ty4 + i) * 128 + bn + tx];
    __syncthreads();
#pragma unroll
    for (int i = 0; i < 4; ++i)
        WT[(size_t)(bn + ty4 + i) * K + bk + tx] = (_Float16)t[tx][ty4 + i];
}

// ---------------- MFMA projection: g0[row0+r] = fp16((feat @ W + b) * ns) --------
template<int K>
__global__ __launch_bounds__(256) void projmm_kernel(
    const float* __restrict__ feat, const _Float16* __restrict__ WT,
    const float* __restrict__ b, const float* __restrict__ ns,
    __half* __restrict__ g0, int row0, int M)
{
    constexpr int LDB = K + 8;
    __shared__ _Float16 BT[128 * LDB];
    int tid = threadIdx.x;
    for (int idx = tid * 8; idx < 128 * K; idx += 256 * 8) {
        int n = idx / K, k = idx % K;
        *(f16x8*)(&BT[n * LDB + k]) = *(const f16x8*)(&WT[n * K + k]);
    }
    __syncthreads();

    int wave = tid >> 6, lane = tid & 63;
    int rb = blockIdx.x * 64 + wave * 16;
    int lr = lane & 15, lk = lane >> 4;

    f32x4 acc[8] = {};
    int arow = rb + lr; if (arow >= M) arow = M - 1;
    const float* afp = feat + (size_t)arow * K;

    for (int k0 = 0; k0 < K; k0 += 32) {
        float4 fa = *(const float4*)(afp + k0 + lk * 8);
        float4 fb = *(const float4*)(afp + k0 + lk * 8 + 4);
        f16x8 a;
        a[0] = (_Float16)fa.x; a[1] = (_Float16)fa.y;
        a[2] = (_Float16)fa.z; a[3] = (_Float16)fa.w;
        a[4] = (_Float16)fb.x; a[5] = (_Float16)fb.y;
        a[6] = (_Float16)fb.z; a[7] = (_Float16)fb.w;
#pragma unroll
        for (int t = 0; t < 8; ++t) {
            f16x8 bf = *(const f16x8*)(&BT[(t * 16 + lr) * LDB + k0 + lk * 8]);
            acc[t] = __builtin_amdgcn_mfma_f32_16x16x32_f16(a, bf, acc[t], 0, 0, 0);
        }
    }

    float bv[8];
#pragma unroll
    for (int t = 0; t < 8; ++t) bv[t] = b[t * 16 + lr];
#pragma unroll
    for (int reg = 0; reg < 4; ++reg) {
        int r = rb + lk * 4 + reg;
        if (r < M) {
            float s = ns[row0 + r];
            size_t base = ((size_t)(row0 + r)) << 7;
#pragma unroll
            for (int t = 0; t < 8; ++t)
                g0[base + t * 16 + lr] = __float2half((acc[t][reg] + bv[t]) * s);
        }
    }
}

// ---------------- one hop: wave per node; 4 subgroups x 16 lanes x 16B ----------
__global__ __launch_bounds__(256) void hop_kernel(
    const __half* __restrict__ gc, __half* __restrict__ gn,
    const unsigned* __restrict__ ideg, const unsigned short* __restrict__ csr,
    const float* __restrict__ nsd)
{
    int node = blockIdx.x * 4 + (threadIdx.x >> 6);
    int lane = threadIdx.x & 63;
    int sub = lane >> 4;
    int ch8 = lane & 15;
    int dd = (int)ideg[node];
    int len = dd > RCAP ? RCAP : ((dd + 15) & ~15);
    int beg = node << 6;
    int end = beg + len;

    float a[8] = {0.f, 0.f, 0.f, 0.f, 0.f, 0.f, 0.f, 0.f};
    for (int base = beg; base < end; base += 16) {
        int i = base + sub;
        int s0 = (int)csr[i];
        int s1 = (int)csr[i + 4];
        int s2 = (int)csr[i + 8];
        int s3 = (int)csr[i + 12];
        int4 v0 = *(const int4*)(gc + ((size_t)s0 << 7) + (ch8 << 3));
        int4 v1 = *(const int4*)(gc + ((size_t)s1 << 7) + (ch8 << 3));
        int4 v2 = *(const int4*)(gc + ((size_t)s2 << 7) + (ch8 << 3));
        int4 v3 = *(const int4*)(gc + ((size_t)s3 << 7) + (ch8 << 3));
        float2 f;
        f = __half22float2(*(__half2*)&v0.x); a[0] += f.x; a[1] += f.y;
        f = __half22float2(*(__half2*)&v0.y); a[2] += f.x; a[3] += f.y;
        f = __half22float2(*(__half2*)&v0.z); a[4] += f.x; a[5] += f.y;
        f = __half22float2(*(__half2*)&v0.w); a[6] += f.x; a[7] += f.y;
        f = __half22float2(*(__half2*)&v1.x); a[0] += f.x; a[1] += f.y;
        f = __half22float2(*(__half2*)&v1.y); a[2] += f.x; a[3] += f.y;
        f = __half22float2(*(__half2*)&v1.z); a[4] += f.x; a[5] += f.y;
        f = __half22float2(*(__half2*)&v1.w); a[6] += f.x; a[7] += f.y;
        f = __half22float2(*(__half2*)&v2.x); a[0] += f.x; a[1] += f.y;
        f = __half22float2(*(__half2*)&v2.y); a[2] += f.x; a[3] += f.y;
        f = __half22float2(*(__half2*)&v2.z); a[4] += f.x; a[5] += f.y;
        f = __half22float2(*(__half2*)&v2.w); a[6] += f.x; a[7] += f.y;
        f = __half22float2(*(__half2*)&v3.x); a[0] += f.x; a[1] += f.y;
        f = __half22float2(*(__half2*)&v3.y); a[2] += f.x; a[3] += f.y;
        f = __half22float2(*(__half2*)&v3.z); a[4] += f.x; a[5] += f.y;
        f = __half22float2(*(__half2*)&v3.w); a[6] += f.x; a[7] += f.y;
    }
#pragma unroll
    for (int j = 0; j < 8; ++j) {
        a[j] += __shfl_xor(a[j], 16);
        a[j] += __shfl_xor(a[j], 32);
    }
    if (sub == 0) {
        float k = nsd[node];
        __half2 h0 = __float22half2_rn(make_float2(a[0] * k, a[1] * k));
        __half2 h1 = __float22half2_rn(make_float2(a[2] * k, a[3] * k));
        __half2 h2 = __float22half2_rn(make_float2(a[4] * k, a[5] * k));
        __half2 h3 = __float22half2_rn(make_float2(a[6] * k, a[7] * k));
        int4 w;
        w.x = *(int*)&h0; w.y = *(int*)&h1; w.z = *(int*)&h2; w.w = *(int*)&h3;
        *(int4*)(gn + ((size_t)node << 7) + (ch8 << 3)) = w;
    }
}

// ---------------- gsum+LN0: xn = LN0((sum_k g_k) * rns / 9), fp16 out ----------
__global__ __launch_bounds__(256) void gsum_ln0_kernel(
    const __half* __restrict__ g, const float* __restrict__ rns,
    const float* __restrict__ ln0g, const float* __restrict__ ln0b,
    __half* __restrict__ xn)
{
    int c = blockIdx.x * 256 + threadIdx.x;
    int node = c >> 4, ch0 = (c & 15) << 3;
    float s8[8] = {0,0,0,0,0,0,0,0};
#pragma unroll
    for (int k = 0; k < 9; ++k) {
        int4 v = *(const int4*)(g + (size_t)k * GSTRIDE + ((size_t)node << 7) + ch0);
        float2 f;
        f = __half22float2(*(__half2*)&v.x); s8[0] += f.x; s8[1] += f.y;
        f = __half22float2(*(__half2*)&v.y); s8[2] += f.x; s8[3] += f.y;
        f = __half22float2(*(__half2*)&v.z); s8[4] += f.x; s8[5] += f.y;
        f = __half22float2(*(__half2*)&v.w); s8[6] += f.x; s8[7] += f.y;
    }
    float sc = rns[node] * (1.0f / 9.0f);
#pragma unroll
    for (int i = 0; i < 8; ++i) s8[i] *= sc;

    // LN0 within the 16-lane node group
    float t = 0.f;
#pragma unroll
    for (int i = 0; i < 8; ++i) t += s8[i];
#pragma unroll
    for (int m = 1; m < 16; m <<= 1) t += __shfl_xor(t, m);
    float mean = t * (1.0f / 128.0f);
    float q = 0.f;
#pragma unroll
    for (int i = 0; i < 8; ++i) { s8[i] -= mean; q += s8[i] * s8[i]; }
#pragma unroll
    for (int m = 1; m < 16; m <<= 1) q += __shfl_xor(q, m);
    float rstd = rsqrtf(q * (1.0f / 128.0f) + 1e-5f);
    float4 ga = *(const float4*)(ln0g + ch0);
    float4 gA = *(const float4*)(ln0g + ch0 + 4);
    float4 ba = *(const float4*)(ln0b + ch0);
    float4 bA = *(const float4*)(ln0b + ch0 + 4);
    __half2 h0 = __float22half2_rn(make_float2(s8[0]*rstd*ga.x + ba.x, s8[1]*rstd*ga.y + ba.y));
    __half2 h1 = __float22half2_rn(make_float2(s8[2]*rstd*ga.z + ba.z, s8[3]*rstd*ga.w + ba.w));
    __half2 h2 = __float22half2_rn(make_float2(s8[4]*rstd*gA.x + bA.x, s8[5]*rstd*gA.y + bA.y));
    __half2 h3 = __float22half2_rn(make_float2(s8[6]*rstd*gA.z + bA.z, s8[7]*rstd*gA.w + bA.w));
    int4 w;
    w.x = *(int*)&h0; w.y = *(int*)&h1; w.z = *(int*)&h2; w.w = *(int*)&h3;
    *(int4*)(xn + ((size_t)node << 7) + ch0) = w;
}

// ---------------- mm2: y = ELU(xn@WpT+bp); LN1; logits = yn@WoT+bo; L2 norm ------
__global__ __launch_bounds__(256) void mm2_kernel(
    const __half* __restrict__ xn, const _Float16* __restrict__ WpT,
    const float* __restrict__ bp,
    const float* __restrict__ ln1g, const float* __restrict__ ln1b,
    const float* __restrict__ Wo, const float* __restrict__ bo,
    float* __restrict__ out)
{
    constexpr int LDB = 136;
    __shared__ _Float16 BT[128 * LDB];
    __shared__ _Float16 WoT[16 * LDB];
    __shared__ _Float16 YN[64 * LDB];
    int tid = threadIdx.x;
    for (int idx = tid * 8; idx < 128 * 128; idx += 256 * 8) {
        int n = idx >> 7, k = idx & 127;
        *(f16x8*)(&BT[n * LDB + k]) = *(const f16x8*)(&WpT[n * 128 + k]);
    }
    for (int idx = tid; idx < 2048; idx += 256) {
        int k = idx >> 4, c = idx & 15;
        WoT[c * LDB + k] = (_Float16)Wo[idx];
    }
    __syncthreads();

    int wave = tid >> 6, lane = tid & 63;
    int lr = lane & 15, lk = lane >> 4;
    int rb = blockIdx.x * 64 + wave * 16;

    // xn @ WpT
    f32x4 acc[8] = {};
    const __half* ap = xn + ((size_t)(rb + lr) << 7);
    for (int k0 = 0; k0 < 128; k0 += 32) {
        f16x8 a = *(const f16x8*)(ap + k0 + lk * 8);
#pragma unroll
        for (int t = 0; t < 8; ++t) {
            f16x8 bf = *(const f16x8*)(&BT[(t * 16 + lr) * LDB + k0 + lk * 8]);
            acc[t] = __builtin_amdgcn_mfma_f32_16x16x32_f16(a, bf, acc[t], 0, 0, 0);
        }
    }

    // epilogue: +bp, ELU, LN1 -> YN fp16 in LDS
    float bv[8], hg[8], hb[8];
#pragma unroll
    for (int t = 0; t < 8; ++t) {
        bv[t] = bp[t * 16 + lr];
        hg[t] = ln1g[t * 16 + lr];
        hb[t] = ln1b[t * 16 + lr];
    }
#pragma unroll
    for (int reg = 0; reg < 4; ++reg) {
        float y[8], S = 0.f;
#pragma unroll
        for (int t = 0; t < 8; ++t) {
            float v = acc[t][reg] + bv[t];
            v = v > 0.f ? v : (expf(v) - 1.f);
            y[t] = v; S += v;
        }
#pragma unroll
        for (int m = 1; m < 16; m <<= 1) S += __shfl_xor(S, m);
        float mean = S * (1.0f / 128.0f);
        float q = 0.f;
#pragma unroll
        for (int t = 0; t < 8; ++t) { y[t] -= mean; q += y[t] * y[t]; }
#pragma unroll
        for (int m = 1; m < 16; m <<= 1) q += __shfl_xor(q, m);
        float rstd = rsqrtf(q * (1.0f / 128.0f) + 1e-5f);
        int row_l = wave * 16 + lk * 4 + reg;
#pragma unroll
        for (int t = 0; t < 8; ++t)
            YN[row_l * LDB + t * 16 + lr] = (_Float16)(y[t] * rstd * hg[t] + hb[t]);
    }
    __syncthreads();

    // head: yn @ WoT (one 16x16 tile per wave), then L2 norm
    f32x4 p = {};
    const _Float16* yrow = &YN[(wave * 16 + lr) * LDB];
    for (int k0 = 0; k0 < 128; k0 += 32) {
        f16x8 a = *(const f16x8*)(yrow + k0 + lk * 8);
        f16x8 bf = *(const f16x8*)(&WoT[lr * LDB + k0 + lk * 8]);
        p = __builtin_amdgcn_mfma_f32_16x16x32_f16(a, bf, p, 0, 0, 0);
    }
    float bol = bo[lr];
#pragma unroll
    for (int reg = 0; reg < 4; ++reg) {
        float logit = p[reg] + bol;
        float ss = logit * logit;
#pragma unroll
        for (int m = 1; m < 16; m <<= 1) ss += __shfl_xor(ss, m);
        float rinv = 1.0f / fmaxf(sqrtf(ss), 1e-12f);
        int row = rb + lk * 4 + reg;
        out[(size_t)row * 16 + lr] = logit * rinv;
    }
}

// ---------------- launch ----------------
extern "C" void kernel_launch(void* const* d_in, const int* in_sizes, int n_in,
                              void* d_out, int out_size, void* d_ws, size_t ws_size,
                              hipStream_t stream)
{
    const float* feat0 = (const float*)d_in[0];
    const float* feat1 = (const float*)d_in[1];
    const int*   src   = (const int*)d_in[2];
    const int*   dst   = (const int*)d_in[3];
    const float* W0    = (const float*)d_in[4];
    const float* b0    = (const float*)d_in[5];
    const float* W1    = (const float*)d_in[6];
    const float* b1    = (const float*)d_in[7];
    const float* ln0_g = (const float*)d_in[8];
    const float* ln0_b = (const float*)d_in[9];
    const float* ln1_g = (const float*)d_in[10];
    const float* ln1_b = (const float*)d_in[11];
    const float* Wp    = (const float*)d_in[12];
    const float* bp    = (const float*)d_in[13];
    const float* Wo    = (const float*)d_in[14];
    const float* bo    = (const float*)d_in[15];
    float* out = (float*)d_out;

    char* ws = (char*)d_ws;
    __half*         gbuf = (__half*)(ws + 0);           // 92,162,304
    float*          ns   = (float*)(ws + 92162304);
    float*          nsd  = (float*)(ws + 92322304);
    float*          rns  = (float*)(ws + 92482304);
    unsigned*       odeg = (unsigned*)(ws + 92642304);
    unsigned*       cnt  = (unsigned*)(ws + 92802304);
    unsigned short* csr  = (unsigned short*)(ws + 92962304); // 5,120,000
    __half*         xbuf = (__half*)(ws + 92962304);    // 10,240,000 (overlay, csr dead)
    _Float16*       WT0  = (_Float16*)(ws + 103202304); // 65,536
    _Float16*       WT1  = (_Float16*)(ws + 103267840); // 32,768
    _Float16*       WpT  = (_Float16*)(ws + 103300608); // 32,768
    // total ~103.3 MB

    hipMemsetAsync(odeg, 0, 320000, stream);

    wtrans_kernel<<<dim3(8, 4), 256, 0, stream>>>(W0, WT0, 256);
    wtrans_kernel<<<dim3(4, 4), 256, 0, stream>>>(W1, WT1, 128);
    wtrans_kernel<<<dim3(4, 4), 256, 0, stream>>>(Wp, WpT, 128);

    fill_kernel<<<2048, 256, 0, stream>>>((unsigned*)csr);
    degbucket_kernel<<<2048, 256, 0, stream>>>(src, dst, odeg, cnt, csr, NE);
    norm_kernel<<<(NN + 255) / 256, 256, 0, stream>>>(odeg, cnt, ns, nsd, rns, NN);
    zero_pad_kernel<<<5, 256, 0, stream>>>(gbuf);

    projmm_kernel<256><<<(NT0 + 63) / 64, 256, 0, stream>>>(feat0, WT0, b0, ns, gbuf, 0, NT0);
    projmm_kernel<128><<<(NT0 + 63) / 64, 256, 0, stream>>>(feat1, WT1, b1, ns, gbuf, NT0, NT0);

    for (int h = 0; h < NHOPS; ++h) {
        hop_kernel<<<NN / 4, 256, 0, stream>>>(gbuf + (size_t)h * GSTRIDE,
                                               gbuf + (size_t)(h + 1) * GSTRIDE,
                                               cnt, csr, nsd);
    }

    gsum_ln0_kernel<<<2500, 256, 0, stream>>>(gbuf, rns, ln0_g, ln0_b, xbuf);
    mm2_kernel<<<NN / 64, 256, 0, stream>>>(xbuf, WpT, bp, ln1_g, ln1_b, Wo, bo, out);
}

// Round 11
// 294.952 us; speedup vs baseline: 1.3814x; 1.0072x over previous
//
#include <hip/hip_runtime.h>
#include <hip/hip_fp16.h>
#include <math.h>

#define NN     40000
#define NT0    20000
#define NE     640000
#define NHOPS  8
#define RCAP   64
#define NSLICE 8
#define SLICEN (NN / NSLICE)
#define GSTRIDE ((size_t)(NN + 1) * 128)

typedef _Float16 f16x8 __attribute__((ext_vector_type(8)));
typedef float    f32x4 __attribute__((ext_vector_type(4)));

// ---------------- init: csr fill + counter zero + g dummy-row zero --------------
__global__ __launch_bounds__(256) void init_kernel(unsigned* __restrict__ csr2,
                                                   unsigned* __restrict__ counters,
                                                   unsigned* __restrict__ gbase)
{
    const unsigned pat = (40000u << 16) | 40000u;
    int tid = blockIdx.x * 256 + threadIdx.x;          // 2048 blocks -> 524288 threads
    for (int u = tid; u < SLICEN * RCAP * NSLICE / 2; u += 524288) csr2[u] = pat;
    if (tid < 80000) counters[tid] = 0u;               // odeg (40000) + cnt (40000)
    if (tid < 9 * 64) {
        int k = tid >> 6, j = tid & 63;
        gbase[(size_t)k * (GSTRIDE / 2) + ((size_t)NN << 6) + j] = 0u;
    }
}

// ---------------- fused degree count + bucket, XCD-sliced, NT edge reads --------
__global__ void degbucket_kernel(const int* __restrict__ src, const int* __restrict__ dst,
                                 unsigned* __restrict__ out_deg, unsigned* __restrict__ cnt,
                                 unsigned short* __restrict__ csr, int E)
{
    int slice = blockIdx.x & 7;
    int lo = slice * SLICEN, hi = lo + SLICEN;
    int pb = blockIdx.x >> 3;
    int start = pb * 256 + threadIdx.x;
    for (int e = start; e < E; e += 65536) {
        int s = __builtin_nontemporal_load(src + e);
        int d = __builtin_nontemporal_load(dst + e);
        if (s >= lo && s < hi) atomicAdd(&out_deg[s], 1u);
        if (d >= lo && d < hi) {
            unsigned p = atomicAdd(&cnt[d], 1u);
            if (p < RCAP) csr[(d << 6) + (int)p] = (unsigned short)s;
        }
    }
}

// ---------------- norms ----------------
__global__ void norm_kernel(const unsigned* __restrict__ out_deg, const unsigned* __restrict__ in_deg,
                            float* __restrict__ ns, float* __restrict__ nsd,
                            float* __restrict__ rns, int n)
{
    int i = blockIdx.x * blockDim.x + threadIdx.x;
    if (i >= n) return;
    float od = fmaxf((float)out_deg[i], 1.0f);
    float s = rsqrtf(od);
    float d = rsqrtf(fmaxf((float)in_deg[i], 1.0f));
    ns[i] = s; nsd[i] = s * d; rns[i] = sqrtf(od);
}

// ---------------- W[K][128] f32 -> WT[128][K] fp16 (tiled transpose) ----------
__global__ __launch_bounds__(256) void wtrans_kernel(const float* __restrict__ W,
                                                     _Float16* __restrict__ WT, int K)
{
    __shared__ float t[32][33];
    int bk = blockIdx.x * 32;
    int bn = blockIdx.y * 32;
    int tx = threadIdx.x & 31, ty4 = (threadIdx.x >> 5) * 4;
#pragma unroll
    for (int i = 0; i < 4; ++i)
        t[ty4 + i][tx] = W[(size_t)(bk + ty4 + i) * 128 + bn + tx];
    __syncthreads();
#pragma unroll
    for (int i = 0; i < 4; ++i)
        WT[(size_t)(bn + ty4 + i) * K + bk + tx] = (_Float16)t[tx][ty4 + i];
}

// ---------------- MFMA projection: g0[row0+r] = fp16((feat @ W + b) * ns) --------
template<int K>
__global__ __launch_bounds__(256) void projmm_kernel(
    const float* __restrict__ feat, const _Float16* __restrict__ WT,
    const float* __restrict__ b, const float* __restrict__ ns,
    __half* __restrict__ g0, int row0, int M)
{
    constexpr int LDB = K + 8;
    __shared__ _Float16 BT[128 * LDB];
    int tid = threadIdx.x;
    for (int idx = tid * 8; idx < 128 * K; idx += 256 * 8) {
        int n = idx / K, k = idx % K;
        *(f16x8*)(&BT[n * LDB + k]) = *(const f16x8*)(&WT[n * K + k]);
    }
    __syncthreads();

    int wave = tid >> 6, lane = tid & 63;
    int rb = blockIdx.x * 64 + wave * 16;
    int lr = lane & 15, lk = lane >> 4;

    f32x4 acc[8] = {};
    int arow = rb + lr; if (arow >= M) arow = M - 1;
    const float* afp = feat + (size_t)arow * K;

    for (int k0 = 0; k0 < K; k0 += 32) {
        float4 fa = *(const float4*)(afp + k0 + lk * 8);
        float4 fb = *(const float4*)(afp + k0 + lk * 8 + 4);
        f16x8 a;
        a[0] = (_Float16)fa.x; a[1] = (_Float16)fa.y;
        a[2] = (_Float16)fa.z; a[3] = (_Float16)fa.w;
        a[4] = (_Float16)fb.x; a[5] = (_Float16)fb.y;
        a[6] = (_Float16)fb.z; a[7] = (_Float16)fb.w;
#pragma unroll
        for (int t = 0; t < 8; ++t) {
            f16x8 bf = *(const f16x8*)(&BT[(t * 16 + lr) * LDB + k0 + lk * 8]);
            acc[t] = __builtin_amdgcn_mfma_f32_16x16x32_f16(a, bf, acc[t], 0, 0, 0);
        }
    }

    float bv[8];
#pragma unroll
    for (int t = 0; t < 8; ++t) bv[t] = b[t * 16 + lr];
#pragma unroll
    for (int reg = 0; reg < 4; ++reg) {
        int r = rb + lk * 4 + reg;
        if (r < M) {
            float s = ns[row0 + r];
            size_t base = ((size_t)(row0 + r)) << 7;
#pragma unroll
            for (int t = 0; t < 8; ++t)
                g0[base + t * 16 + lr] = __float2half((acc[t][reg] + bv[t]) * s);
        }
    }
}

// ---------------- one hop: wave per node; 4 subgroups x 16 lanes x 16B ----------
__global__ __launch_bounds__(256) void hop_kernel(
    const __half* __restrict__ gc, __half* __restrict__ gn,
    const unsigned* __restrict__ ideg, const unsigned short* __restrict__ csr,
    const float* __restrict__ nsd)
{
    int node = blockIdx.x * 4 + (threadIdx.x >> 6);
    int lane = threadIdx.x & 63;
    int sub = lane >> 4;
    int ch8 = lane & 15;
    int dd = (int)ideg[node];
    int len = dd > RCAP ? RCAP : ((dd + 15) & ~15);
    int beg = node << 6;
    int end = beg + len;

    float a[8] = {0.f, 0.f, 0.f, 0.f, 0.f, 0.f, 0.f, 0.f};
    for (int base = beg; base < end; base += 16) {
        int i = base + sub;
        int s0 = (int)csr[i];
        int s1 = (int)csr[i + 4];
        int s2 = (int)csr[i + 8];
        int s3 = (int)csr[i + 12];
        int4 v0 = *(const int4*)(gc + ((size_t)s0 << 7) + (ch8 << 3));
        int4 v1 = *(const int4*)(gc + ((size_t)s1 << 7) + (ch8 << 3));
        int4 v2 = *(const int4*)(gc + ((size_t)s2 << 7) + (ch8 << 3));
        int4 v3 = *(const int4*)(gc + ((size_t)s3 << 7) + (ch8 << 3));
        float2 f;
        f = __half22float2(*(__half2*)&v0.x); a[0] += f.x; a[1] += f.y;
        f = __half22float2(*(__half2*)&v0.y); a[2] += f.x; a[3] += f.y;
        f = __half22float2(*(__half2*)&v0.z); a[4] += f.x; a[5] += f.y;
        f = __half22float2(*(__half2*)&v0.w); a[6] += f.x; a[7] += f.y;
        f = __half22float2(*(__half2*)&v1.x); a[0] += f.x; a[1] += f.y;
        f = __half22float2(*(__half2*)&v1.y); a[2] += f.x; a[3] += f.y;
        f = __half22float2(*(__half2*)&v1.z); a[4] += f.x; a[5] += f.y;
        f = __half22float2(*(__half2*)&v1.w); a[6] += f.x; a[7] += f.y;
        f = __half22float2(*(__half2*)&v2.x); a[0] += f.x; a[1] += f.y;
        f = __half22float2(*(__half2*)&v2.y); a[2] += f.x; a[3] += f.y;
        f = __half22float2(*(__half2*)&v2.z); a[4] += f.x; a[5] += f.y;
        f = __half22float2(*(__half2*)&v2.w); a[6] += f.x; a[7] += f.y;
        f = __half22float2(*(__half2*)&v3.x); a[0] += f.x; a[1] += f.y;
        f = __half22float2(*(__half2*)&v3.y); a[2] += f.x; a[3] += f.y;
        f = __half22float2(*(__half2*)&v3.z); a[4] += f.x; a[5] += f.y;
        f = __half22float2(*(__half2*)&v3.w); a[6] += f.x; a[7] += f.y;
    }
#pragma unroll
    for (int j = 0; j < 8; ++j) {
        a[j] += __shfl_xor(a[j], 16);
        a[j] += __shfl_xor(a[j], 32);
    }
    if (sub == 0) {
        float k = nsd[node];
        __half2 h0 = __float22half2_rn(make_float2(a[0] * k, a[1] * k));
        __half2 h1 = __float22half2_rn(make_float2(a[2] * k, a[3] * k));
        __half2 h2 = __float22half2_rn(make_float2(a[4] * k, a[5] * k));
        __half2 h3 = __float22half2_rn(make_float2(a[6] * k, a[7] * k));
        int4 w;
        w.x = *(int*)&h0; w.y = *(int*)&h1; w.z = *(int*)&h2; w.w = *(int*)&h3;
        *(int4*)(gn + ((size_t)node << 7) + (ch8 << 3)) = w;
    }
}

// ---------------- gsum+LN0: xn = LN0((sum_k g_k) * rns / 9), fp16 out ----------
__global__ __launch_bounds__(256) void gsum_ln0_kernel(
    const __half* __restrict__ g, const float* __restrict__ rns,
    const float* __restrict__ ln0g, const float* __restrict__ ln0b,
    __half* __restrict__ xn)
{
    int c = blockIdx.x * 256 + threadIdx.x;
    int node = c >> 4, ch0 = (c & 15) << 3;
    float s8[8] = {0,0,0,0,0,0,0,0};
#pragma unroll
    for (int k = 0; k < 9; ++k) {
        int4 v = *(const int4*)(g + (size_t)k * GSTRIDE + ((size_t)node << 7) + ch0);
        float2 f;
        f = __half22float2(*(__half2*)&v.x); s8[0] += f.x; s8[1] += f.y;
        f = __half22float2(*(__half2*)&v.y); s8[2] += f.x; s8[3] += f.y;
        f = __half22float2(*(__half2*)&v.z); s8[4] += f.x; s8[5] += f.y;
        f = __half22float2(*(__half2*)&v.w); s8[6] += f.x; s8[7] += f.y;
    }
    float sc = rns[node] * (1.0f / 9.0f);
#pragma unroll
    for (int i = 0; i < 8; ++i) s8[i] *= sc;

    float t = 0.f;
#pragma unroll
    for (int i = 0; i < 8; ++i) t += s8[i];
#pragma unroll
    for (int m = 1; m < 16; m <<= 1) t += __shfl_xor(t, m);
    float mean = t * (1.0f / 128.0f);
    float q = 0.f;
#pragma unroll
    for (int i = 0; i < 8; ++i) { s8[i] -= mean; q += s8[i] * s8[i]; }
#pragma unroll
    for (int m = 1; m < 16; m <<= 1) q += __shfl_xor(q, m);
    float rstd = rsqrtf(q * (1.0f / 128.0f) + 1e-5f);
    float4 ga = *(const float4*)(ln0g + ch0);
    float4 gA = *(const float4*)(ln0g + ch0 + 4);
    float4 ba = *(const float4*)(ln0b + ch0);
    float4 bA = *(const float4*)(ln0b + ch0 + 4);
    __half2 h0 = __float22half2_rn(make_float2(s8[0]*rstd*ga.x + ba.x, s8[1]*rstd*ga.y + ba.y));
    __half2 h1 = __float22half2_rn(make_float2(s8[2]*rstd*ga.z + ba.z, s8[3]*rstd*ga.w + ba.w));
    __half2 h2 = __float22half2_rn(make_float2(s8[4]*rstd*gA.x + bA.x, s8[5]*rstd*gA.y + bA.y));
    __half2 h3 = __float22half2_rn(make_float2(s8[6]*rstd*gA.z + bA.z, s8[7]*rstd*gA.w + bA.w));
    int4 w;
    w.x = *(int*)&h0; w.y = *(int*)&h1; w.z = *(int*)&h2; w.w = *(int*)&h3;
    *(int4*)(xn + ((size_t)node << 7) + ch0) = w;
}

// ---------------- mm2: y = ELU(xn@WpT+bp); LN1; logits = yn@WoT+bo; L2 norm ------
__global__ __launch_bounds__(256) void mm2_kernel(
    const __half* __restrict__ xn, const _Float16* __restrict__ WpT,
    const float* __restrict__ bp,
    const float* __restrict__ ln1g, const float* __restrict__ ln1b,
    const float* __restrict__ Wo, const float* __restrict__ bo,
    float* __restrict__ out)
{
    constexpr int LDB = 136;
    __shared__ _Float16 BT[128 * LDB];
    __shared__ _Float16 WoT[16 * LDB];
    __shared__ _Float16 YN[64 * LDB];
    int tid = threadIdx.x;
    for (int idx = tid * 8; idx < 128 * 128; idx += 256 * 8) {
        int n = idx >> 7, k = idx & 127;
        *(f16x8*)(&BT[n * LDB + k]) = *(const f16x8*)(&WpT[n * 128 + k]);
    }
    for (int idx = tid; idx < 2048; idx += 256) {
        int k = idx >> 4, c = idx & 15;
        WoT[c * LDB + k] = (_Float16)Wo[idx];
    }
    __syncthreads();

    int wave = tid >> 6, lane = tid & 63;
    int lr = lane & 15, lk = lane >> 4;
    int rb = blockIdx.x * 64 + wave * 16;

    f32x4 acc[8] = {};
    const __half* ap = xn + ((size_t)(rb + lr) << 7);
    for (int k0 = 0; k0 < 128; k0 += 32) {
        f16x8 a = *(const f16x8*)(ap + k0 + lk * 8);
#pragma unroll
        for (int t = 0; t < 8; ++t) {
            f16x8 bf = *(const f16x8*)(&BT[(t * 16 + lr) * LDB + k0 + lk * 8]);
            acc[t] = __builtin_amdgcn_mfma_f32_16x16x32_f16(a, bf, acc[t], 0, 0, 0);
        }
    }

    float bv[8], hg[8], hb[8];
#pragma unroll
    for (int t = 0; t < 8; ++t) {
        bv[t] = bp[t * 16 + lr];
        hg[t] = ln1g[t * 16 + lr];
        hb[t] = ln1b[t * 16 + lr];
    }
#pragma unroll
    for (int reg = 0; reg < 4; ++reg) {
        float y[8], S = 0.f;
#pragma unroll
        for (int t = 0; t < 8; ++t) {
            float v = acc[t][reg] + bv[t];
            v = v > 0.f ? v : (expf(v) - 1.f);
            y[t] = v; S += v;
        }
#pragma unroll
        for (int m = 1; m < 16; m <<= 1) S += __shfl_xor(S, m);
        float mean = S * (1.0f / 128.0f);
        float q = 0.f;
#pragma unroll
        for (int t = 0; t < 8; ++t) { y[t] -= mean; q += y[t] * y[t]; }
#pragma unroll
        for (int m = 1; m < 16; m <<= 1) q += __shfl_xor(q, m);
        float rstd = rsqrtf(q * (1.0f / 128.0f) + 1e-5f);
        int row_l = wave * 16 + lk * 4 + reg;
#pragma unroll
        for (int t = 0; t < 8; ++t)
            YN[row_l * LDB + t * 16 + lr] = (_Float16)(y[t] * rstd * hg[t] + hb[t]);
    }
    __syncthreads();

    f32x4 p = {};
    const _Float16* yrow = &YN[(wave * 16 + lr) * LDB];
    for (int k0 = 0; k0 < 128; k0 += 32) {
        f16x8 a = *(const f16x8*)(yrow + k0 + lk * 8);
        f16x8 bf = *(const f16x8*)(&WoT[lr * LDB + k0 + lk * 8]);
        p = __builtin_amdgcn_mfma_f32_16x16x32_f16(a, bf, p, 0, 0, 0);
    }
    float bol = bo[lr];
#pragma unroll
    for (int reg = 0; reg < 4; ++reg) {
        float logit = p[reg] + bol;
        float ss = logit * logit;
#pragma unroll
        for (int m = 1; m < 16; m <<= 1) ss += __shfl_xor(ss, m);
        float rinv = 1.0f / fmaxf(sqrtf(ss), 1e-12f);
        int row = rb + lk * 4 + reg;
        out[(size_t)row * 16 + lr] = logit * rinv;
    }
}

// ---------------- launch ----------------
extern "C" void kernel_launch(void* const* d_in, const int* in_sizes, int n_in,
                              void* d_out, int out_size, void* d_ws, size_t ws_size,
                              hipStream_t stream)
{
    const float* feat0 = (const float*)d_in[0];
    const float* feat1 = (const float*)d_in[1];
    const int*   src   = (const int*)d_in[2];
    const int*   dst   = (const int*)d_in[3];
    const float* W0    = (const float*)d_in[4];
    const float* b0    = (const float*)d_in[5];
    const float* W1    = (const float*)d_in[6];
    const float* b1    = (const float*)d_in[7];
    const float* ln0_g = (const float*)d_in[8];
    const float* ln0_b = (const float*)d_in[9];
    const float* ln1_g = (const float*)d_in[10];
    const float* ln1_b = (const float*)d_in[11];
    const float* Wp    = (const float*)d_in[12];
    const float* bp    = (const float*)d_in[13];
    const float* Wo    = (const float*)d_in[14];
    const float* bo    = (const float*)d_in[15];
    float* out = (float*)d_out;

    char* ws = (char*)d_ws;
    __half*         gbuf = (__half*)(ws + 0);           // 92,162,304
    float*          ns   = (float*)(ws + 92162304);
    float*          nsd  = (float*)(ws + 92322304);
    float*          rns  = (float*)(ws + 92482304);
    unsigned*       odeg = (unsigned*)(ws + 92642304);  // odeg+cnt contiguous 320KB
    unsigned*       cnt  = (unsigned*)(ws + 92802304);
    unsigned short* csr  = (unsigned short*)(ws + 92962304); // 5,120,000
    __half*         xbuf = (__half*)(ws + 92962304);    // overlay (csr dead after hops)
    _Float16*       WT0  = (_Float16*)(ws + 103202304);
    _Float16*       WT1  = (_Float16*)(ws + 103267840);
    _Float16*       WpT  = (_Float16*)(ws + 103300608);
    // total ~103.3 MB

    wtrans_kernel<<<dim3(8, 4), 256, 0, stream>>>(W0, WT0, 256);
    wtrans_kernel<<<dim3(4, 4), 256, 0, stream>>>(W1, WT1, 128);
    wtrans_kernel<<<dim3(4, 4), 256, 0, stream>>>(Wp, WpT, 128);

    init_kernel<<<2048, 256, 0, stream>>>((unsigned*)csr, odeg, (unsigned*)gbuf);
    degbucket_kernel<<<2048, 256, 0, stream>>>(src, dst, odeg, cnt, csr, NE);
    norm_kernel<<<(NN + 255) / 256, 256, 0, stream>>>(odeg, cnt, ns, nsd, rns, NN);

    projmm_kernel<256><<<(NT0 + 63) / 64, 256, 0, stream>>>(feat0, WT0, b0, ns, gbuf, 0, NT0);
    projmm_kernel<128><<<(NT0 + 63) / 64, 256, 0, stream>>>(feat1, WT1, b1, ns, gbuf, NT0, NT0);

    for (int h = 0; h < NHOPS; ++h) {
        hop_kernel<<<NN / 4, 256, 0, stream>>>(gbuf + (size_t)h * GSTRIDE,
                                               gbuf + (size_t)(h + 1) * GSTRIDE,
                                               cnt, csr, nsd);
    }

    gsum_ln0_kernel<<<2500, 256, 0, stream>>>(gbuf, rns, ln0_g, ln0_b, xbuf);
    mm2_kernel<<<NN / 64, 256, 0, stream>>>(xbuf, WpT, bp, ln1_g, ln1_b, Wo, bo, out);
}